// Round 5
// baseline (3162.340 us; speedup 1.0000x reference)
//
#include <hip/hip_runtime.h>
#include <math.h>

#define D 768
#define T 1024
#define BATCH 2
#define NH 12
#define NL 12
#define V 50257
#define NT 2048  // BATCH*T

typedef _Float16 half4_t __attribute__((ext_vector_type(4)));
typedef _Float16 half8_t __attribute__((ext_vector_type(8)));
typedef float floatx4 __attribute__((ext_vector_type(4)));

// ---------------- wave helpers ----------------
__device__ inline float wave_reduce_sum(float v) {
  #pragma unroll
  for (int off = 32; off > 0; off >>= 1) v += __shfl_xor(v, off, 64);
  return v;
}

// direct HBM->LDS, 16B per lane (1KB per wave-instruction)
__device__ __forceinline__ void gld16(const _Float16* g, _Float16* l) {
  __builtin_amdgcn_global_load_lds(
      (const __attribute__((address_space(1))) unsigned int*)g,
      (__attribute__((address_space(3))) unsigned int*)l, 16, 0, 0);
}

// ---------------- embedding ----------------
__global__ __launch_bounds__(256) void embed_kernel(const int* __restrict__ idx,
    const float* __restrict__ wte, const float* __restrict__ pos,
    float* __restrict__ x) {
  int row = blockIdx.x;                 // 0..NT-1
  int tok = idx[row];
  int tp  = row & (T - 1);
  const float* ws = wte + (size_t)tok * D;
  const float* ps = pos + (size_t)tp * D;
  float* xr = x + (size_t)row * D;
  for (int i = threadIdx.x; i < D; i += 256) xr[i] = ws[i] + ps[i];
}

// ---------------- fp32 -> fp16 bulk convert (wte) ----------------
__global__ __launch_bounds__(256) void cvt16_kernel(const float* __restrict__ src,
    _Float16* __restrict__ dst, int n4) {
  int i = blockIdx.x * 256 + threadIdx.x;
  int stride = gridDim.x * 256;
  for (; i < n4; i += stride) {
    float4 v = ((const float4*)src)[i];
    half4_t h;
    h[0] = (_Float16)v.x; h[1] = (_Float16)v.y;
    h[2] = (_Float16)v.z; h[3] = (_Float16)v.w;
    ((half4_t*)dst)[i] = h;
  }
}

// ---------------- weight convert+transpose: [K,N]f32 -> [N,K]f16 ----------------
__global__ __launch_bounds__(256) void wconv_kernel(
    const float* __restrict__ qkvw, const float* __restrict__ projw,
    const float* __restrict__ fc1w, const float* __restrict__ fc2w,
    _Float16* __restrict__ q16, _Float16* __restrict__ p16,
    _Float16* __restrict__ f116, _Float16* __restrict__ f216) {
  int id = blockIdx.x;
  size_t l = blockIdx.y;
  const float* src; _Float16* dst; int K, N, tn;
  if (id < 1728)      { src = qkvw + l * (D * 3 * D); dst = q16  + l * (2304 * 768); K = 768;  N = 2304; tn = id; }
  else if (id < 2304) { src = projw + l * (D * D);    dst = p16  + l * (768 * 768);  K = 768;  N = 768;  tn = id - 1728; }
  else if (id < 4608) { src = fc1w + l * (D * 4 * D); dst = f116 + l * (3072 * 768); K = 768;  N = 3072; tn = id - 2304; }
  else                { src = fc2w + l * (4 * D * D); dst = f216 + l * (3072 * 768); K = 3072; N = 768;  tn = id - 4608; }
  int ntn = N >> 5;
  int tc = (tn % ntn) * 32;   // n0
  int tr = (tn / ntn) * 32;   // k0
  __shared__ float tile[32][33];
  int tx = threadIdx.x & 31, ty = threadIdx.x >> 5;
  #pragma unroll
  for (int j = 0; j < 4; ++j)
    tile[ty + 8 * j][tx] = src[(size_t)(tr + ty + 8 * j) * N + tc + tx];
  __syncthreads();
  #pragma unroll
  for (int j = 0; j < 4; ++j)
    dst[(size_t)(tc + ty + 8 * j) * K + tr + tx] = (_Float16)tile[tx][ty + 8 * j];
}

// ---------------- layernorm: one wave per row, float4 loads, single pass ------
__global__ __launch_bounds__(256) void ln_kernel(const float* __restrict__ x,
    const float* __restrict__ g, const float* __restrict__ bta,
    _Float16* __restrict__ y) {
  const int lane = threadIdx.x & 63, wave = threadIdx.x >> 6;
  const int row = blockIdx.x * 4 + wave;
  const float4* xr = (const float4*)(x + (size_t)row * D);
  half4_t* yr = (half4_t*)(y + (size_t)row * D);

  float4 a[3];
  #pragma unroll
  for (int j = 0; j < 3; ++j) a[j] = xr[lane + 64 * j];

  float s = 0.f;
  #pragma unroll
  for (int j = 0; j < 3; ++j) s += a[j].x + a[j].y + a[j].z + a[j].w;
  float mean = wave_reduce_sum(s) * (1.f / D);

  float v = 0.f;
  #pragma unroll
  for (int j = 0; j < 3; ++j) {
    float dx = a[j].x - mean, dy = a[j].y - mean, dz = a[j].z - mean, dw = a[j].w - mean;
    v += dx * dx + dy * dy + dz * dz + dw * dw;
  }
  float rstd = rsqrtf(wave_reduce_sum(v) * (1.f / D) + 1e-5f);

  #pragma unroll
  for (int j = 0; j < 3; ++j) {
    float4 gg = ((const float4*)g)[lane + 64 * j];
    float4 bb = ((const float4*)bta)[lane + 64 * j];
    half4_t h;
    h[0] = (_Float16)((a[j].x - mean) * rstd * gg.x + bb.x);
    h[1] = (_Float16)((a[j].y - mean) * rstd * gg.y + bb.y);
    h[2] = (_Float16)((a[j].z - mean) * rstd * gg.z + bb.z);
    h[3] = (_Float16)((a[j].w - mean) * rstd * gg.w + bb.w);
    yr[lane + 64 * j] = h;
  }
}

// ---------------- MFMA flash attention, 2-phase double-buffered ----------------
__global__ __launch_bounds__(256) void attn_kernel(
    const _Float16* __restrict__ qkv,   // [NT, 3D] fp16 (Q at 0, K at D)
    const _Float16* __restrict__ vt,    // [B*NH*64, T] fp16 (V transposed)
    _Float16* __restrict__ o) {         // [NT, D] fp16
  const int qt   = (int)gridDim.x - 1 - (int)blockIdx.x;
  const int h    = blockIdx.y;
  const int b    = blockIdx.z;
  const int tid  = threadIdx.x;
  const int lane = tid & 63, wave = tid >> 6;
  const int lr = lane & 15, g = lane >> 4;
  const int lk = g * 8;   // frag k-offset (halves)
  const int cr = g * 4;   // C-fragment row base

  __shared__ __align__(16) _Float16 Ks[2][2][64][32];   // [buf][dstep][key][d-half]
  __shared__ __align__(16) _Float16 Vs[2][2][64][32];   // [buf][kstep][d][key-half]
  __shared__ __align__(16) _Float16 Pl[4][16][72];      // per-wave P[q][k]

  const int RS = 3 * D;
  const int q0 = qt * 64 + wave * 16;

  const _Float16* qrow = qkv + (size_t)(b * T + q0 + lr) * RS + h * 64;
  half8_t aq0 = *(const half8_t*)(qrow + lk);
  half8_t aq1 = *(const half8_t*)(qrow + 32 + lk);
  #pragma unroll
  for (int j = 0; j < 8; ++j) { aq0[j] *= (_Float16)0.125f; aq1[j] *= (_Float16)0.125f; }

  const int sr = wave * 16 + (lane >> 2);
  const int sc = (lane & 3) * 8;
  const _Float16* ksrc = qkv + (size_t)(b * T + sr) * RS + D + h * 64 + sc;
  const _Float16* vsrc = vt + (size_t)((b * NH + h) * 64 + sr) * T + sc;

#define ASTAGE(bufn, kk) do {                                   \
    const _Float16* kp_ = ksrc + (size_t)((kk) * 64) * RS;      \
    gld16(kp_,      &Ks[bufn][0][wave * 16][0]);                \
    gld16(kp_ + 32, &Ks[bufn][1][wave * 16][0]);                \
    gld16(vsrc + (kk) * 64,      &Vs[bufn][0][wave * 16][0]);   \
    gld16(vsrc + (kk) * 64 + 32, &Vs[bufn][1][wave * 16][0]);   \
  } while (0)

  floatx4 oa[4] = {};
  float m_r[4] = {-1e30f, -1e30f, -1e30f, -1e30f};
  float l_r[4] = {0.f, 0.f, 0.f, 0.f};

  ASTAGE(0, 0);
  __syncthreads();   // compiler drains vmcnt(0) before barrier

  for (int kt = 0; kt <= qt; ++kt) {
    const int cur = kt & 1;
    if (kt < qt) ASTAGE(cur ^ 1, kt + 1);   // prefetch next tile (overlaps compute)

    floatx4 s4[4];
    #pragma unroll
    for (int kc = 0; kc < 4; ++kc) {
      half8_t bk0 = *(const half8_t*)&Ks[cur][0][kc * 16 + lr][lk];
      half8_t bk1 = *(const half8_t*)&Ks[cur][1][kc * 16 + lr][lk];
      floatx4 z = {};
      z = __builtin_amdgcn_mfma_f32_16x16x32_f16(aq0, bk0, z, 0, 0, 0);
      z = __builtin_amdgcn_mfma_f32_16x16x32_f16(aq1, bk1, z, 0, 0, 0);
      s4[kc] = z;
    }
    if (kt == qt) {
      #pragma unroll
      for (int kc = 0; kc < 4; ++kc)
        #pragma unroll
        for (int i = 0; i < 4; ++i)
          if (kc * 16 + lr > wave * 16 + cr + i) s4[kc][i] = -1e30f;
    }

    float alpha[4], psum[4];
    #pragma unroll
    for (int i = 0; i < 4; ++i) {
      float v = fmaxf(fmaxf(s4[0][i], s4[1][i]), fmaxf(s4[2][i], s4[3][i]));
      #pragma unroll
      for (int off = 1; off < 16; off <<= 1) v = fmaxf(v, __shfl_xor(v, off, 64));
      float mn = fmaxf(m_r[i], v);
      alpha[i] = __expf(m_r[i] - mn);
      m_r[i] = mn;
      psum[i] = 0.f;
    }
    #pragma unroll
    for (int kc = 0; kc < 4; ++kc)
      #pragma unroll
      for (int i = 0; i < 4; ++i) {
        float p = __expf(s4[kc][i] - m_r[i]);
        psum[i] += p;
        Pl[wave][cr + i][kc * 16 + lr] = (_Float16)p;
      }
    #pragma unroll
    for (int i = 0; i < 4; ++i) {
      float s = psum[i];
      #pragma unroll
      for (int off = 1; off < 16; off <<= 1) s += __shfl_xor(s, off, 64);
      l_r[i] = l_r[i] * alpha[i] + s;
    }
    #pragma unroll
    for (int dc = 0; dc < 4; ++dc)
      #pragma unroll
      for (int i = 0; i < 4; ++i) oa[dc][i] *= alpha[i];

    half8_t ap0 = *(const half8_t*)&Pl[wave][lr][lk];
    half8_t ap1 = *(const half8_t*)&Pl[wave][lr][32 + lk];
    #pragma unroll
    for (int dc = 0; dc < 4; ++dc) {
      half8_t bv0 = *(const half8_t*)&Vs[cur][0][dc * 16 + lr][lk];
      half8_t bv1 = *(const half8_t*)&Vs[cur][1][dc * 16 + lr][lk];
      oa[dc] = __builtin_amdgcn_mfma_f32_16x16x32_f16(ap0, bv0, oa[dc], 0, 0, 0);
      oa[dc] = __builtin_amdgcn_mfma_f32_16x16x32_f16(ap1, bv1, oa[dc], 0, 0, 0);
    }
    __syncthreads();   // one barrier per tile: drains prefetch + protects buffers
  }
#undef ASTAGE

  _Float16* orow = o + (size_t)(b * T + q0) * D + h * 64;
  #pragma unroll
  for (int i = 0; i < 4; ++i) {
    float inv = 1.f / l_r[i];
    #pragma unroll
    for (int dc = 0; dc < 4; ++dc)
      orow[(size_t)(cr + i) * D + dc * 16 + lr] = (_Float16)(oa[dc][i] * inv);
  }
}

// ---------------- fp16 MFMA GEMM, 2-phase double-buffered ----------------
// C[M,N] = A[M,K] @ Bt[N,K]^T (+bias,+res,+GELU). A,Bt fp16 K-contiguous.
// n-major XCD-chunked tile mapping; split-K via ATOMIC; VT scatters V third
// transposed; NTS uses non-temporal stores (write-once output, e.g. logits).
template <bool GELU, bool VT, bool ATOMIC, bool NTS, typename OutT>
__global__ __launch_bounds__(256) void gemm16_kernel(
    const _Float16* __restrict__ A, const _Float16* __restrict__ Bt,
    const float* __restrict__ bias, const float* __restrict__ res,
    OutT* __restrict__ C, _Float16* __restrict__ vt, int M, int N, int K) {
  __shared__ __align__(16) _Float16 As[2][128][32];
  __shared__ __align__(16) _Float16 Bs[2][128][32];
  const int t = threadIdx.x;
  const int lane = t & 63, wave = t >> 6;

  // n-major XCD-chunked tile mapping (nwg % 8 == 0 in all launches)
  const int gx = gridDim.x, gy = gridDim.y;
  const int nwg = gx * gy;
  int f = blockIdx.y * gx + blockIdx.x;         // HW dispatch order (x fastest)
  int id = (f & 7) * (nwg >> 3) + (f >> 3);     // XCD gets contiguous chunk
  const int n0 = (id / gy) * 128;               // n-major within chunk
  const int m0 = (id % gy) * 128;

  // split-K range
  const int ks = K / gridDim.z;
  const int kbeg = blockIdx.z * ks, kend = kbeg + ks;

  const int wm = (wave >> 1) * 64, wn = (wave & 1) * 64;
  const int lr = lane & 15;            // frag row (A) / col (B)
  const int lk = (lane >> 4) * 8;      // frag k-offset (halves)

  const int srow = lane >> 2;          // 0..15
  const int scol = (lane & 3) * 8;     // halves
  const _Float16* a_src0 = A + (size_t)(m0 + wave * 32 + srow) * K + scol;
  const _Float16* a_src1 = a_src0 + (size_t)16 * K;
  const int bn0 = min(n0 + wave * 32 + srow, N - 1);       // clamp (logits tail)
  const int bn1 = min(n0 + wave * 32 + 16 + srow, N - 1);
  const _Float16* b_src0 = Bt + (size_t)bn0 * K + scol;
  const _Float16* b_src1 = Bt + (size_t)bn1 * K + scol;

#define GSTAGE(bufn, kk) do {                            \
    gld16(a_src0 + (kk), &As[bufn][wave * 32][0]);       \
    gld16(a_src1 + (kk), &As[bufn][wave * 32 + 16][0]);  \
    gld16(b_src0 + (kk), &Bs[bufn][wave * 32][0]);       \
    gld16(b_src1 + (kk), &Bs[bufn][wave * 32 + 16][0]);  \
  } while (0)

  floatx4 acc[4][4] = {};

  GSTAGE(0, kbeg);
  __syncthreads();   // vmcnt(0) drained by compiler before barrier

  const int nIter = (kend - kbeg) >> 5;
  for (int i = 0; i < nIter; ++i) {
    const int cur = i & 1;
    if (i + 1 < nIter) GSTAGE(cur ^ 1, kbeg + ((i + 1) << 5));  // prefetch

    half8_t af[4], bb[4];
    #pragma unroll
    for (int mi = 0; mi < 4; ++mi)
      af[mi] = *(const half8_t*)&As[cur][wm + mi * 16 + lr][lk];
    #pragma unroll
    for (int ni = 0; ni < 4; ++ni)
      bb[ni] = *(const half8_t*)&Bs[cur][wn + ni * 16 + lr][lk];
    #pragma unroll
    for (int mi = 0; mi < 4; ++mi)
      #pragma unroll
      for (int ni = 0; ni < 4; ++ni)
        acc[mi][ni] = __builtin_amdgcn_mfma_f32_16x16x32_f16(
            af[mi], bb[ni], acc[mi][ni], 0, 0, 0);
    __syncthreads();   // one barrier per K-step
  }
#undef GSTAGE

  // epilogue: C/D layout col=lane&15, row=(lane>>4)*4+reg
  const int cr = (lane >> 4) * 4;
  #pragma unroll
  for (int mi = 0; mi < 4; ++mi) {
    #pragma unroll
    for (int ni = 0; ni < 4; ++ni) {
      int n = n0 + wn + ni * 16 + lr;
      if (n >= N) continue;
      floatx4 v = acc[mi][ni];
      float bs = (bias && (!ATOMIC || blockIdx.z == 0)) ? bias[n] : 0.f;
      if (VT && n >= 2 * D) {
        int d  = n - 2 * D;
        int mb = m0 + wm + mi * 16 + cr;
        half4_t h4;
        #pragma unroll
        for (int i = 0; i < 4; ++i) h4[i] = (_Float16)(v[i] + bs);
        *(half4_t*)(vt + ((size_t)((mb >> 10) * NH + (d >> 6)) * 64 + (d & 63)) * T
                       + (mb & 1023)) = h4;
      } else if (ATOMIC) {
        #pragma unroll
        for (int i = 0; i < 4; ++i) {
          int m = m0 + wm + mi * 16 + cr + i;
          atomicAdd((float*)&C[(size_t)m * N + n], v[i] + bs);
        }
      } else {
        #pragma unroll
        for (int i = 0; i < 4; ++i) {
          int m = m0 + wm + mi * 16 + cr + i;
          float vv = v[i] + bs;
          if (res)  vv += res[(size_t)m * N + n];
          if (GELU) vv = 0.5f * vv * (1.f + erff(vv * 0.70710678118f));
          if (NTS) __builtin_nontemporal_store((OutT)vv, &C[(size_t)m * N + n]);
          else     C[(size_t)m * N + n] = (OutT)vv;
        }
      }
    }
  }
}

// ---------------- launcher ----------------
extern "C" void kernel_launch(void* const* d_in, const int* in_sizes, int n_in,
                              void* d_out, int out_size, void* d_ws, size_t ws_size,
                              hipStream_t stream) {
  const int*   idx   = (const int*)d_in[0];
  const float* wte   = (const float*)d_in[1];
  const float* pos   = (const float*)d_in[2];
  const float* ln1g  = (const float*)d_in[3];
  const float* ln1b  = (const float*)d_in[4];
  const float* qkvw  = (const float*)d_in[5];
  const float* qkvb  = (const float*)d_in[6];
  const float* projw = (const float*)d_in[7];
  const float* projb = (const float*)d_in[8];
  const float* ln2g  = (const float*)d_in[9];
  const float* ln2b  = (const float*)d_in[10];
  const float* fc1w  = (const float*)d_in[11];
  const float* fc1b  = (const float*)d_in[12];
  const float* fc2w  = (const float*)d_in[13];
  const float* fc2b  = (const float*)d_in[14];
  const float* lnfg  = (const float*)d_in[15];
  const float* lnfb  = (const float*)d_in[16];
  float* out = (float*)d_out;

  // ---- workspace layout ----
  float* ws = (float*)d_ws;
  float* x = ws;                                        // [NT, D] f32 residual
  _Float16* big16  = (_Float16*)(x + (size_t)NT * D);   // [NT,4D]
  _Float16* vt16   = big16 + (size_t)NT * 4 * D;        // [B*NH*64, T]
  _Float16* hbuf16 = vt16 + (size_t)BATCH * NH * 64 * T;// [NT, D]
  _Float16* obuf16 = hbuf16 + (size_t)NT * D;           // [NT, D]
  _Float16* wte16  = obuf16 + (size_t)NT * D;           // [V, D]
  _Float16* wbase  = wte16 + (size_t)V * D;             // weights (1 or 12 layers)

  const size_t QSZ = (size_t)2304 * 768, PSZ = (size_t)768 * 768;
  const size_t F1SZ = (size_t)3072 * 768, F2SZ = (size_t)3072 * 768;
  const size_t PERL = QSZ + PSZ + F1SZ + F2SZ;          // 7,077,888 halves
  const size_t fixed_bytes = (char*)wbase - (char*)d_ws;
  const bool all12 = ws_size >= fixed_bytes + 12 * PERL * sizeof(_Float16);
  const int nlw = all12 ? 12 : 1;

  _Float16* q16  = wbase;
  _Float16* p16  = q16  + QSZ * nlw;
  _Float16* f116 = p16  + PSZ * nlw;
  _Float16* f216 = f116 + F1SZ * nlw;

  cvt16_kernel<<<2048, 256, 0, stream>>>(wte, wte16, (V * D) / 4);
  embed_kernel<<<NT, 256, 0, stream>>>(idx, wte, pos, x);
  if (all12)
    wconv_kernel<<<dim3(6912, 12), 256, 0, stream>>>(
        qkvw, projw, fc1w, fc2w, q16, p16, f116, f216);

  for (int l = 0; l < NL; ++l) {
    size_t lw = all12 ? (size_t)l : 0;
    if (!all12)
      wconv_kernel<<<dim3(6912, 1), 256, 0, stream>>>(
          qkvw + (size_t)l * D * 3 * D, projw + (size_t)l * D * D,
          fc1w + (size_t)l * D * 4 * D, fc2w + (size_t)l * 4 * D * D,
          q16, p16, f116, f216);
    // ln1 -> fp16
    ln_kernel<<<NT / 4, 256, 0, stream>>>(x, ln1g + (size_t)l * D, ln1b + (size_t)l * D, hbuf16);
    // qkv: Q,K -> big16 [NT,3D]; V -> vt16 transposed
    gemm16_kernel<false, true, false, false, _Float16><<<dim3(18, 16), 256, 0, stream>>>(
        hbuf16, q16 + lw * QSZ, qkvb + (size_t)l * 3 * D, nullptr, big16, vt16, NT, 3 * D, D);
    // flash attention -> obuf16
    attn_kernel<<<dim3(T / 64, NH, BATCH), 256, 0, stream>>>(big16, vt16, obuf16);
    // x += o @ proj_w + proj_b  (split-K=2, atomic into residual)
    gemm16_kernel<false, false, true, false, float><<<dim3(6, 16, 2), 256, 0, stream>>>(
        obuf16, p16 + lw * PSZ, projb + (size_t)l * D, nullptr, x, nullptr, NT, D, D);
    // ln2 -> fp16
    ln_kernel<<<NT / 4, 256, 0, stream>>>(x, ln2g + (size_t)l * D, ln2b + (size_t)l * D, hbuf16);
    // fc1 + GELU -> big16 (fp16 [NT,4D])
    gemm16_kernel<true, false, false, false, _Float16><<<dim3(24, 16), 256, 0, stream>>>(
        hbuf16, f116 + lw * F1SZ, fc1b + (size_t)l * 4 * D, nullptr, big16, nullptr, NT, 4 * D, D);
    // x += gelu @ fc2_w + fc2_b  (split-K=4, atomic into residual)
    gemm16_kernel<false, false, true, false, float><<<dim3(6, 16, 4), 256, 0, stream>>>(
        big16, f216 + lw * F2SZ, fc2b + (size_t)l * D, nullptr, x, nullptr, NT, D, 4 * D);
  }

  // final LN -> fp16
  ln_kernel<<<NT / 4, 256, 0, stream>>>(x, lnfg, lnfb, hbuf16);
  // logits = h @ wte^T   [NT, V]  (non-temporal stores: write-once output)
  gemm16_kernel<false, false, false, true, float><<<dim3((V + 127) / 128, 16), 256, 0, stream>>>(
      hbuf16, wte16, nullptr, nullptr, out, nullptr, NT, V, D);
}

// Round 6
// 2775.031 us; speedup vs baseline: 1.1396x; 1.1396x over previous
//
#include <hip/hip_runtime.h>
#include <math.h>

#define D 768
#define T 1024
#define BATCH 2
#define NH 12
#define NL 12
#define V 50257
#define NT 2048  // BATCH*T

typedef _Float16 half4_t __attribute__((ext_vector_type(4)));
typedef _Float16 half8_t __attribute__((ext_vector_type(8)));
typedef float floatx4 __attribute__((ext_vector_type(4)));

// ---------------- wave helpers ----------------
__device__ inline float wave_reduce_sum(float v) {
  #pragma unroll
  for (int off = 32; off > 0; off >>= 1) v += __shfl_xor(v, off, 64);
  return v;
}

// direct HBM->LDS, 16B per lane (1KB per wave-instruction)
__device__ __forceinline__ void gld16(const _Float16* g, _Float16* l) {
  __builtin_amdgcn_global_load_lds(
      (const __attribute__((address_space(1))) unsigned int*)g,
      (__attribute__((address_space(3))) unsigned int*)l, 16, 0, 0);
}

// ---------------- embedding ----------------
__global__ __launch_bounds__(256) void embed_kernel(const int* __restrict__ idx,
    const float* __restrict__ wte, const float* __restrict__ pos,
    float* __restrict__ x) {
  int row = blockIdx.x;                 // 0..NT-1
  int tok = idx[row];
  int tp  = row & (T - 1);
  const float* ws = wte + (size_t)tok * D;
  const float* ps = pos + (size_t)tp * D;
  float* xr = x + (size_t)row * D;
  for (int i = threadIdx.x; i < D; i += 256) xr[i] = ws[i] + ps[i];
}

// ---------------- fp32 -> fp16 bulk convert (wte) ----------------
__global__ __launch_bounds__(256) void cvt16_kernel(const float* __restrict__ src,
    _Float16* __restrict__ dst, int n4) {
  int i = blockIdx.x * 256 + threadIdx.x;
  int stride = gridDim.x * 256;
  for (; i < n4; i += stride) {
    float4 v = ((const float4*)src)[i];
    half4_t h;
    h[0] = (_Float16)v.x; h[1] = (_Float16)v.y;
    h[2] = (_Float16)v.z; h[3] = (_Float16)v.w;
    ((half4_t*)dst)[i] = h;
  }
}

// ---------------- weight convert+transpose: [K,N]f32 -> [N,K]f16 ----------------
__global__ __launch_bounds__(256) void wconv_kernel(
    const float* __restrict__ qkvw, const float* __restrict__ projw,
    const float* __restrict__ fc1w, const float* __restrict__ fc2w,
    _Float16* __restrict__ q16, _Float16* __restrict__ p16,
    _Float16* __restrict__ f116, _Float16* __restrict__ f216) {
  int id = blockIdx.x;
  size_t l = blockIdx.y;
  const float* src; _Float16* dst; int K, N, tn;
  if (id < 1728)      { src = qkvw + l * (D * 3 * D); dst = q16  + l * (2304 * 768); K = 768;  N = 2304; tn = id; }
  else if (id < 2304) { src = projw + l * (D * D);    dst = p16  + l * (768 * 768);  K = 768;  N = 768;  tn = id - 1728; }
  else if (id < 4608) { src = fc1w + l * (D * 4 * D); dst = f116 + l * (3072 * 768); K = 768;  N = 3072; tn = id - 2304; }
  else                { src = fc2w + l * (4 * D * D); dst = f216 + l * (3072 * 768); K = 3072; N = 768;  tn = id - 4608; }
  int ntn = N >> 5;
  int tc = (tn % ntn) * 32;   // n0
  int tr = (tn / ntn) * 32;   // k0
  __shared__ float tile[32][33];
  int tx = threadIdx.x & 31, ty = threadIdx.x >> 5;
  #pragma unroll
  for (int j = 0; j < 4; ++j)
    tile[ty + 8 * j][tx] = src[(size_t)(tr + ty + 8 * j) * N + tc + tx];
  __syncthreads();
  #pragma unroll
  for (int j = 0; j < 4; ++j)
    dst[(size_t)(tc + ty + 8 * j) * K + tr + tx] = (_Float16)tile[tx][ty + 8 * j];
}

// ---------------- layernorm: one wave per row, float4 loads, single pass ------
__global__ __launch_bounds__(256) void ln_kernel(const float* __restrict__ x,
    const float* __restrict__ g, const float* __restrict__ bta,
    _Float16* __restrict__ y) {
  const int lane = threadIdx.x & 63, wave = threadIdx.x >> 6;
  const int row = blockIdx.x * 4 + wave;
  const float4* xr = (const float4*)(x + (size_t)row * D);
  half4_t* yr = (half4_t*)(y + (size_t)row * D);

  float4 a[3];
  #pragma unroll
  for (int j = 0; j < 3; ++j) a[j] = xr[lane + 64 * j];

  float s = 0.f;
  #pragma unroll
  for (int j = 0; j < 3; ++j) s += a[j].x + a[j].y + a[j].z + a[j].w;
  float mean = wave_reduce_sum(s) * (1.f / D);

  float v = 0.f;
  #pragma unroll
  for (int j = 0; j < 3; ++j) {
    float dx = a[j].x - mean, dy = a[j].y - mean, dz = a[j].z - mean, dw = a[j].w - mean;
    v += dx * dx + dy * dy + dz * dz + dw * dw;
  }
  float rstd = rsqrtf(wave_reduce_sum(v) * (1.f / D) + 1e-5f);

  #pragma unroll
  for (int j = 0; j < 3; ++j) {
    float4 gg = ((const float4*)g)[lane + 64 * j];
    float4 bb = ((const float4*)bta)[lane + 64 * j];
    half4_t h;
    h[0] = (_Float16)((a[j].x - mean) * rstd * gg.x + bb.x);
    h[1] = (_Float16)((a[j].y - mean) * rstd * gg.y + bb.y);
    h[2] = (_Float16)((a[j].z - mean) * rstd * gg.z + bb.z);
    h[3] = (_Float16)((a[j].w - mean) * rstd * gg.w + bb.w);
    yr[lane + 64 * j] = h;
  }
}

// ---------------- MFMA flash attention, 2-phase double-buffered ----------------
__global__ __launch_bounds__(256) void attn_kernel(
    const _Float16* __restrict__ qkv,   // [NT, 3D] fp16 (Q at 0, K at D)
    const _Float16* __restrict__ vt,    // [B*NH*64, T] fp16 (V transposed)
    _Float16* __restrict__ o) {         // [NT, D] fp16
  const int qt   = (int)gridDim.x - 1 - (int)blockIdx.x;
  const int h    = blockIdx.y;
  const int b    = blockIdx.z;
  const int tid  = threadIdx.x;
  const int lane = tid & 63, wave = tid >> 6;
  const int lr = lane & 15, g = lane >> 4;
  const int lk = g * 8;   // frag k-offset (halves)
  const int cr = g * 4;   // C-fragment row base

  __shared__ __align__(16) _Float16 Ks[2][2][64][32];   // [buf][dstep][key][d-half]
  __shared__ __align__(16) _Float16 Vs[2][2][64][32];   // [buf][kstep][d][key-half]
  __shared__ __align__(16) _Float16 Pl[4][16][72];      // per-wave P[q][k]

  const int RS = 3 * D;
  const int q0 = qt * 64 + wave * 16;

  const _Float16* qrow = qkv + (size_t)(b * T + q0 + lr) * RS + h * 64;
  half8_t aq0 = *(const half8_t*)(qrow + lk);
  half8_t aq1 = *(const half8_t*)(qrow + 32 + lk);
  #pragma unroll
  for (int j = 0; j < 8; ++j) { aq0[j] *= (_Float16)0.125f; aq1[j] *= (_Float16)0.125f; }

  const int sr = wave * 16 + (lane >> 2);
  const int sc = (lane & 3) * 8;
  const _Float16* ksrc = qkv + (size_t)(b * T + sr) * RS + D + h * 64 + sc;
  const _Float16* vsrc = vt + (size_t)((b * NH + h) * 64 + sr) * T + sc;

#define ASTAGE(bufn, kk) do {                                   \
    const _Float16* kp_ = ksrc + (size_t)((kk) * 64) * RS;      \
    gld16(kp_,      &Ks[bufn][0][wave * 16][0]);                \
    gld16(kp_ + 32, &Ks[bufn][1][wave * 16][0]);                \
    gld16(vsrc + (kk) * 64,      &Vs[bufn][0][wave * 16][0]);   \
    gld16(vsrc + (kk) * 64 + 32, &Vs[bufn][1][wave * 16][0]);   \
  } while (0)

  floatx4 oa[4] = {};
  float m_r[4] = {-1e30f, -1e30f, -1e30f, -1e30f};
  float l_r[4] = {0.f, 0.f, 0.f, 0.f};

  ASTAGE(0, 0);
  __syncthreads();   // compiler drains vmcnt(0) before barrier

  for (int kt = 0; kt <= qt; ++kt) {
    const int cur = kt & 1;
    if (kt < qt) ASTAGE(cur ^ 1, kt + 1);   // prefetch next tile (overlaps compute)

    floatx4 s4[4];
    #pragma unroll
    for (int kc = 0; kc < 4; ++kc) {
      half8_t bk0 = *(const half8_t*)&Ks[cur][0][kc * 16 + lr][lk];
      half8_t bk1 = *(const half8_t*)&Ks[cur][1][kc * 16 + lr][lk];
      floatx4 z = {};
      z = __builtin_amdgcn_mfma_f32_16x16x32_f16(aq0, bk0, z, 0, 0, 0);
      z = __builtin_amdgcn_mfma_f32_16x16x32_f16(aq1, bk1, z, 0, 0, 0);
      s4[kc] = z;
    }
    if (kt == qt) {
      #pragma unroll
      for (int kc = 0; kc < 4; ++kc)
        #pragma unroll
        for (int i = 0; i < 4; ++i)
          if (kc * 16 + lr > wave * 16 + cr + i) s4[kc][i] = -1e30f;
    }

    float alpha[4], psum[4];
    #pragma unroll
    for (int i = 0; i < 4; ++i) {
      float v = fmaxf(fmaxf(s4[0][i], s4[1][i]), fmaxf(s4[2][i], s4[3][i]));
      #pragma unroll
      for (int off = 1; off < 16; off <<= 1) v = fmaxf(v, __shfl_xor(v, off, 64));
      float mn = fmaxf(m_r[i], v);
      alpha[i] = __expf(m_r[i] - mn);
      m_r[i] = mn;
      psum[i] = 0.f;
    }
    #pragma unroll
    for (int kc = 0; kc < 4; ++kc)
      #pragma unroll
      for (int i = 0; i < 4; ++i) {
        float p = __expf(s4[kc][i] - m_r[i]);
        psum[i] += p;
        Pl[wave][cr + i][kc * 16 + lr] = (_Float16)p;
      }
    #pragma unroll
    for (int i = 0; i < 4; ++i) {
      float s = psum[i];
      #pragma unroll
      for (int off = 1; off < 16; off <<= 1) s += __shfl_xor(s, off, 64);
      l_r[i] = l_r[i] * alpha[i] + s;
    }
    #pragma unroll
    for (int dc = 0; dc < 4; ++dc)
      #pragma unroll
      for (int i = 0; i < 4; ++i) oa[dc][i] *= alpha[i];

    half8_t ap0 = *(const half8_t*)&Pl[wave][lr][lk];
    half8_t ap1 = *(const half8_t*)&Pl[wave][lr][32 + lk];
    #pragma unroll
    for (int dc = 0; dc < 4; ++dc) {
      half8_t bv0 = *(const half8_t*)&Vs[cur][0][dc * 16 + lr][lk];
      half8_t bv1 = *(const half8_t*)&Vs[cur][1][dc * 16 + lr][lk];
      oa[dc] = __builtin_amdgcn_mfma_f32_16x16x32_f16(ap0, bv0, oa[dc], 0, 0, 0);
      oa[dc] = __builtin_amdgcn_mfma_f32_16x16x32_f16(ap1, bv1, oa[dc], 0, 0, 0);
    }
    __syncthreads();   // one barrier per tile: drains prefetch + protects buffers
  }
#undef ASTAGE

  _Float16* orow = o + (size_t)(b * T + q0) * D + h * 64;
  #pragma unroll
  for (int i = 0; i < 4; ++i) {
    float inv = 1.f / l_r[i];
    #pragma unroll
    for (int dc = 0; dc < 4; ++dc)
      orow[(size_t)(cr + i) * D + dc * 16 + lr] = (_Float16)(oa[dc][i] * inv);
  }
}

// ---------------- fp16 MFMA GEMM, 2-phase double-buffered ----------------
// C[M,N] = A[M,K] @ Bt[N,K]^T (+bias,+res,+GELU). A,Bt fp16 K-contiguous.
// n-major XCD-chunked tile mapping; split-K via ATOMIC; VT scatters V third
// transposed. NTS (logits): staged LDS epilogue + full-line non-temporal
// stores (no bias/res/GELU on this path).
template <bool GELU, bool VT, bool ATOMIC, bool NTS, typename OutT>
__global__ __launch_bounds__(256) void gemm16_kernel(
    const _Float16* __restrict__ A, const _Float16* __restrict__ Bt,
    const float* __restrict__ bias, const float* __restrict__ res,
    OutT* __restrict__ C, _Float16* __restrict__ vt, int M, int N, int K) {
  // union: K-loop staging (2 bufs x (A+B) x 128x32 fp16 = 32768 B)
  //        NTS epilogue fp32 tile [64][132] = 33792 B
  __shared__ __align__(16) char smem_raw[33792];
  _Float16 (*As)[128][32] = (_Float16(*)[128][32])smem_raw;            // [2][128][32]
  _Float16 (*Bs)[128][32] = (_Float16(*)[128][32])(smem_raw + 16384);  // [2][128][32]

  const int t = threadIdx.x;
  const int lane = t & 63, wave = t >> 6;

  // n-major XCD-chunked tile mapping (nwg % 8 == 0 in all launches)
  const int gx = gridDim.x, gy = gridDim.y;
  const int nwg = gx * gy;
  int f = blockIdx.y * gx + blockIdx.x;         // HW dispatch order (x fastest)
  int id = (f & 7) * (nwg >> 3) + (f >> 3);     // XCD gets contiguous chunk
  const int n0 = (id / gy) * 128;               // n-major within chunk
  const int m0 = (id % gy) * 128;

  // split-K range
  const int ks = K / gridDim.z;
  const int kbeg = blockIdx.z * ks, kend = kbeg + ks;

  const int wm = (wave >> 1) * 64, wn = (wave & 1) * 64;
  const int lr = lane & 15;            // frag row (A) / col (B)
  const int lk = (lane >> 4) * 8;      // frag k-offset (halves)

  const int srow = lane >> 2;          // 0..15
  const int scol = (lane & 3) * 8;     // halves
  const _Float16* a_src0 = A + (size_t)(m0 + wave * 32 + srow) * K + scol;
  const _Float16* a_src1 = a_src0 + (size_t)16 * K;
  const int bn0 = min(n0 + wave * 32 + srow, N - 1);       // clamp (logits tail)
  const int bn1 = min(n0 + wave * 32 + 16 + srow, N - 1);
  const _Float16* b_src0 = Bt + (size_t)bn0 * K + scol;
  const _Float16* b_src1 = Bt + (size_t)bn1 * K + scol;

#define GSTAGE(bufn, kk) do {                            \
    gld16(a_src0 + (kk), &As[bufn][wave * 32][0]);       \
    gld16(a_src1 + (kk), &As[bufn][wave * 32 + 16][0]);  \
    gld16(b_src0 + (kk), &Bs[bufn][wave * 32][0]);       \
    gld16(b_src1 + (kk), &Bs[bufn][wave * 32 + 16][0]);  \
  } while (0)

  floatx4 acc[4][4] = {};

  GSTAGE(0, kbeg);
  __syncthreads();   // vmcnt(0) drained by compiler before barrier

  const int nIter = (kend - kbeg) >> 5;
  for (int i = 0; i < nIter; ++i) {
    const int cur = i & 1;
    if (i + 1 < nIter) GSTAGE(cur ^ 1, kbeg + ((i + 1) << 5));  // prefetch

    half8_t af[4], bb[4];
    #pragma unroll
    for (int mi = 0; mi < 4; ++mi)
      af[mi] = *(const half8_t*)&As[cur][wm + mi * 16 + lr][lk];
    #pragma unroll
    for (int ni = 0; ni < 4; ++ni)
      bb[ni] = *(const half8_t*)&Bs[cur][wn + ni * 16 + lr][lk];
    #pragma unroll
    for (int mi = 0; mi < 4; ++mi)
      #pragma unroll
      for (int ni = 0; ni < 4; ++ni)
        acc[mi][ni] = __builtin_amdgcn_mfma_f32_16x16x32_f16(
            af[mi], bb[ni], acc[mi][ni], 0, 0, 0);
    __syncthreads();   // one barrier per K-step
  }
#undef GSTAGE

  const int cr = (lane >> 4) * 4;

  if (NTS) {
    // staged epilogue: per 64-row half, dump acc to LDS fp32 [64][132],
    // then stream out 64-consecutive-floats-per-wave NT stores (full lines).
    float (*ob)[132] = (float(*)[132])smem_raw;
    #pragma unroll
    for (int h2 = 0; h2 < 2; ++h2) {
      __syncthreads();
      if ((wave >> 1) == h2) {
        #pragma unroll
        for (int mi = 0; mi < 4; ++mi)
          #pragma unroll
          for (int ni = 0; ni < 4; ++ni) {
            floatx4 v = acc[mi][ni];
            #pragma unroll
            for (int i = 0; i < 4; ++i)
              ob[mi * 16 + cr + i][wn + ni * 16 + lr] = v[i];
          }
      }
      __syncthreads();
      const int col = t & 127;           // 128 cols over 2 half-waves
      const int n = n0 + col;
      if (n < N) {
        #pragma unroll
        for (int r2 = 0; r2 < 32; ++r2) {
          int rloc = r2 * 2 + (t >> 7);
          int m = m0 + h2 * 64 + rloc;
          __builtin_nontemporal_store((OutT)ob[rloc][col], &C[(size_t)m * N + n]);
        }
      }
    }
    return;
  }

  // epilogue: C/D layout col=lane&15, row=(lane>>4)*4+reg
  #pragma unroll
  for (int mi = 0; mi < 4; ++mi) {
    #pragma unroll
    for (int ni = 0; ni < 4; ++ni) {
      int n = n0 + wn + ni * 16 + lr;
      if (n >= N) continue;
      floatx4 v = acc[mi][ni];
      float bs = (bias && (!ATOMIC || blockIdx.z == 0)) ? bias[n] : 0.f;
      if (VT && n >= 2 * D) {
        int d  = n - 2 * D;
        int mb = m0 + wm + mi * 16 + cr;
        half4_t h4;
        #pragma unroll
        for (int i = 0; i < 4; ++i) h4[i] = (_Float16)(v[i] + bs);
        *(half4_t*)(vt + ((size_t)((mb >> 10) * NH + (d >> 6)) * 64 + (d & 63)) * T
                       + (mb & 1023)) = h4;
      } else if (ATOMIC) {
        #pragma unroll
        for (int i = 0; i < 4; ++i) {
          int m = m0 + wm + mi * 16 + cr + i;
          atomicAdd((float*)&C[(size_t)m * N + n], v[i] + bs);
        }
      } else {
        #pragma unroll
        for (int i = 0; i < 4; ++i) {
          int m = m0 + wm + mi * 16 + cr + i;
          float vv = v[i] + bs;
          if (res)  vv += res[(size_t)m * N + n];
          if (GELU) vv = 0.5f * vv * (1.f + erff(vv * 0.70710678118f));
          C[(size_t)m * N + n] = (OutT)vv;
        }
      }
    }
  }
}

// ---------------- launcher ----------------
extern "C" void kernel_launch(void* const* d_in, const int* in_sizes, int n_in,
                              void* d_out, int out_size, void* d_ws, size_t ws_size,
                              hipStream_t stream) {
  const int*   idx   = (const int*)d_in[0];
  const float* wte   = (const float*)d_in[1];
  const float* pos   = (const float*)d_in[2];
  const float* ln1g  = (const float*)d_in[3];
  const float* ln1b  = (const float*)d_in[4];
  const float* qkvw  = (const float*)d_in[5];
  const float* qkvb  = (const float*)d_in[6];
  const float* projw = (const float*)d_in[7];
  const float* projb = (const float*)d_in[8];
  const float* ln2g  = (const float*)d_in[9];
  const float* ln2b  = (const float*)d_in[10];
  const float* fc1w  = (const float*)d_in[11];
  const float* fc1b  = (const float*)d_in[12];
  const float* fc2w  = (const float*)d_in[13];
  const float* fc2b  = (const float*)d_in[14];
  const float* lnfg  = (const float*)d_in[15];
  const float* lnfb  = (const float*)d_in[16];
  float* out = (float*)d_out;

  // ---- workspace layout ----
  float* ws = (float*)d_ws;
  float* x = ws;                                        // [NT, D] f32 residual
  _Float16* big16  = (_Float16*)(x + (size_t)NT * D);   // [NT,4D]
  _Float16* vt16   = big16 + (size_t)NT * 4 * D;        // [B*NH*64, T]
  _Float16* hbuf16 = vt16 + (size_t)BATCH * NH * 64 * T;// [NT, D]
  _Float16* obuf16 = hbuf16 + (size_t)NT * D;           // [NT, D]
  _Float16* wte16  = obuf16 + (size_t)NT * D;           // [V, D]
  _Float16* wbase  = wte16 + (size_t)V * D;             // weights (1 or 12 layers)

  const size_t QSZ = (size_t)2304 * 768, PSZ = (size_t)768 * 768;
  const size_t F1SZ = (size_t)3072 * 768, F2SZ = (size_t)3072 * 768;
  const size_t PERL = QSZ + PSZ + F1SZ + F2SZ;          // 7,077,888 halves
  const size_t fixed_bytes = (char*)wbase - (char*)d_ws;
  const bool all12 = ws_size >= fixed_bytes + 12 * PERL * sizeof(_Float16);
  const int nlw = all12 ? 12 : 1;

  _Float16* q16  = wbase;
  _Float16* p16  = q16  + QSZ * nlw;
  _Float16* f116 = p16  + PSZ * nlw;
  _Float16* f216 = f116 + F1SZ * nlw;

  cvt16_kernel<<<2048, 256, 0, stream>>>(wte, wte16, (V * D) / 4);
  embed_kernel<<<NT, 256, 0, stream>>>(idx, wte, pos, x);
  if (all12)
    wconv_kernel<<<dim3(6912, 12), 256, 0, stream>>>(
        qkvw, projw, fc1w, fc2w, q16, p16, f116, f216);

  for (int l = 0; l < NL; ++l) {
    size_t lw = all12 ? (size_t)l : 0;
    if (!all12)
      wconv_kernel<<<dim3(6912, 1), 256, 0, stream>>>(
          qkvw + (size_t)l * D * 3 * D, projw + (size_t)l * D * D,
          fc1w + (size_t)l * D * 4 * D, fc2w + (size_t)l * 4 * D * D,
          q16, p16, f116, f216);
    // ln1 -> fp16
    ln_kernel<<<NT / 4, 256, 0, stream>>>(x, ln1g + (size_t)l * D, ln1b + (size_t)l * D, hbuf16);
    // qkv: Q,K -> big16 [NT,3D]; V -> vt16 transposed
    gemm16_kernel<false, true, false, false, _Float16><<<dim3(18, 16), 256, 0, stream>>>(
        hbuf16, q16 + lw * QSZ, qkvb + (size_t)l * 3 * D, nullptr, big16, vt16, NT, 3 * D, D);
    // flash attention -> obuf16
    attn_kernel<<<dim3(T / 64, NH, BATCH), 256, 0, stream>>>(big16, vt16, obuf16);
    // x += o @ proj_w + proj_b  (split-K=2, atomic into residual)
    gemm16_kernel<false, false, true, false, float><<<dim3(6, 16, 2), 256, 0, stream>>>(
        obuf16, p16 + lw * PSZ, projb + (size_t)l * D, nullptr, x, nullptr, NT, D, D);
    // ln2 -> fp16
    ln_kernel<<<NT / 4, 256, 0, stream>>>(x, ln2g + (size_t)l * D, ln2b + (size_t)l * D, hbuf16);
    // fc1 + GELU -> big16 (fp16 [NT,4D])
    gemm16_kernel<true, false, false, false, _Float16><<<dim3(24, 16), 256, 0, stream>>>(
        hbuf16, f116 + lw * F1SZ, fc1b + (size_t)l * 4 * D, nullptr, big16, nullptr, NT, 4 * D, D);
    // x += gelu @ fc2_w + fc2_b  (split-K=4, atomic into residual)
    gemm16_kernel<false, false, true, false, float><<<dim3(6, 16, 4), 256, 0, stream>>>(
        big16, f216 + lw * F2SZ, fc2b + (size_t)l * D, nullptr, x, nullptr, NT, D, 4 * D);
  }

  // final LN -> fp16
  ln_kernel<<<NT / 4, 256, 0, stream>>>(x, lnfg, lnfb, hbuf16);
  // logits = h @ wte^T   [NT, V]  (staged + full-line non-temporal stores)
  gemm16_kernel<false, false, false, true, float><<<dim3((V + 127) / 128, 16), 256, 0, stream>>>(
      hbuf16, wte16, nullptr, nullptr, out, nullptr, NT, V, D);
}

// Round 8
// 2659.609 us; speedup vs baseline: 1.1890x; 1.0434x over previous
//
#include <hip/hip_runtime.h>
#include <math.h>

#define D 768
#define T 1024
#define BATCH 2
#define NH 12
#define NL 12
#define V 50257
#define NT 2048  // BATCH*T

typedef _Float16 half4_t __attribute__((ext_vector_type(4)));
typedef _Float16 half8_t __attribute__((ext_vector_type(8)));
typedef float floatx4 __attribute__((ext_vector_type(4)));

// ---------------- wave helpers ----------------
__device__ inline float wave_reduce_sum(float v) {
  #pragma unroll
  for (int off = 32; off > 0; off >>= 1) v += __shfl_xor(v, off, 64);
  return v;
}

// direct HBM->LDS, 16B per lane (1KB per wave-instruction)
__device__ __forceinline__ void gld16(const _Float16* g, _Float16* l) {
  __builtin_amdgcn_global_load_lds(
      (const __attribute__((address_space(1))) unsigned int*)g,
      (__attribute__((address_space(3))) unsigned int*)l, 16, 0, 0);
}

// counted vmcnt wait — full literal coverage; conservative fallback
template <int N> __device__ __forceinline__ void waitvm() {
  if constexpr (N == 8)      asm volatile("s_waitcnt vmcnt(8)" ::: "memory");
  else if constexpr (N == 7) asm volatile("s_waitcnt vmcnt(7)" ::: "memory");
  else if constexpr (N == 6) asm volatile("s_waitcnt vmcnt(6)" ::: "memory");
  else if constexpr (N == 5) asm volatile("s_waitcnt vmcnt(5)" ::: "memory");
  else if constexpr (N == 4) asm volatile("s_waitcnt vmcnt(4)" ::: "memory");
  else if constexpr (N == 3) asm volatile("s_waitcnt vmcnt(3)" ::: "memory");
  else if constexpr (N == 2) asm volatile("s_waitcnt vmcnt(2)" ::: "memory");
  else if constexpr (N == 1) asm volatile("s_waitcnt vmcnt(1)" ::: "memory");
  else                       asm volatile("s_waitcnt vmcnt(0)" ::: "memory");
}

// ---------------- embedding ----------------
__global__ __launch_bounds__(256) void embed_kernel(const int* __restrict__ idx,
    const float* __restrict__ wte, const float* __restrict__ pos,
    float* __restrict__ x) {
  int row = blockIdx.x;                 // 0..NT-1
  int tok = idx[row];
  int tp  = row & (T - 1);
  const float* ws = wte + (size_t)tok * D;
  const float* ps = pos + (size_t)tp * D;
  float* xr = x + (size_t)row * D;
  for (int i = threadIdx.x; i < D; i += 256) xr[i] = ws[i] + ps[i];
}

// ---------------- fp32 -> fp16 bulk convert (wte) ----------------
__global__ __launch_bounds__(256) void cvt16_kernel(const float* __restrict__ src,
    _Float16* __restrict__ dst, int n4) {
  int i = blockIdx.x * 256 + threadIdx.x;
  int stride = gridDim.x * 256;
  for (; i < n4; i += stride) {
    float4 v = ((const float4*)src)[i];
    half4_t h;
    h[0] = (_Float16)v.x; h[1] = (_Float16)v.y;
    h[2] = (_Float16)v.z; h[3] = (_Float16)v.w;
    ((half4_t*)dst)[i] = h;
  }
}

// ---------------- weight convert+transpose: [K,N]f32 -> [N,K]f16 ----------------
__global__ __launch_bounds__(256) void wconv_kernel(
    const float* __restrict__ qkvw, const float* __restrict__ projw,
    const float* __restrict__ fc1w, const float* __restrict__ fc2w,
    _Float16* __restrict__ q16, _Float16* __restrict__ p16,
    _Float16* __restrict__ f116, _Float16* __restrict__ f216) {
  int id = blockIdx.x;
  size_t l = blockIdx.y;
  const float* src; _Float16* dst; int K, N, tn;
  if (id < 1728)      { src = qkvw + l * (D * 3 * D); dst = q16  + l * (2304 * 768); K = 768;  N = 2304; tn = id; }
  else if (id < 2304) { src = projw + l * (D * D);    dst = p16  + l * (768 * 768);  K = 768;  N = 768;  tn = id - 1728; }
  else if (id < 4608) { src = fc1w + l * (D * 4 * D); dst = f116 + l * (3072 * 768); K = 768;  N = 3072; tn = id - 2304; }
  else                { src = fc2w + l * (4 * D * D); dst = f216 + l * (3072 * 768); K = 3072; N = 768;  tn = id - 4608; }
  int ntn = N >> 5;
  int tc = (tn % ntn) * 32;   // n0
  int tr = (tn / ntn) * 32;   // k0
  __shared__ float tile[32][33];
  int tx = threadIdx.x & 31, ty = threadIdx.x >> 5;
  #pragma unroll
  for (int j = 0; j < 4; ++j)
    tile[ty + 8 * j][tx] = src[(size_t)(tr + ty + 8 * j) * N + tc + tx];
  __syncthreads();
  #pragma unroll
  for (int j = 0; j < 4; ++j)
    dst[(size_t)(tc + ty + 8 * j) * K + tr + tx] = (_Float16)tile[tx][ty + 8 * j];
}

// ---------------- layernorm: one wave per row, float4 loads, single pass ------
__global__ __launch_bounds__(256) void ln_kernel(const float* __restrict__ x,
    const float* __restrict__ g, const float* __restrict__ bta,
    _Float16* __restrict__ y) {
  const int lane = threadIdx.x & 63, wave = threadIdx.x >> 6;
  const int row = blockIdx.x * 4 + wave;
  const float4* xr = (const float4*)(x + (size_t)row * D);
  half4_t* yr = (half4_t*)(y + (size_t)row * D);

  float4 a[3];
  #pragma unroll
  for (int j = 0; j < 3; ++j) a[j] = xr[lane + 64 * j];

  float s = 0.f;
  #pragma unroll
  for (int j = 0; j < 3; ++j) s += a[j].x + a[j].y + a[j].z + a[j].w;
  float mean = wave_reduce_sum(s) * (1.f / D);

  float v = 0.f;
  #pragma unroll
  for (int j = 0; j < 3; ++j) {
    float dx = a[j].x - mean, dy = a[j].y - mean, dz = a[j].z - mean, dw = a[j].w - mean;
    v += dx * dx + dy * dy + dz * dz + dw * dw;
  }
  float rstd = rsqrtf(wave_reduce_sum(v) * (1.f / D) + 1e-5f);

  #pragma unroll
  for (int j = 0; j < 3; ++j) {
    float4 gg = ((const float4*)g)[lane + 64 * j];
    float4 bb = ((const float4*)bta)[lane + 64 * j];
    half4_t h;
    h[0] = (_Float16)((a[j].x - mean) * rstd * gg.x + bb.x);
    h[1] = (_Float16)((a[j].y - mean) * rstd * gg.y + bb.y);
    h[2] = (_Float16)((a[j].z - mean) * rstd * gg.z + bb.z);
    h[3] = (_Float16)((a[j].w - mean) * rstd * gg.w + bb.w);
    yr[lane + 64 * j] = h;
  }
}

// ---------------- MFMA flash attention, 2-phase double-buffered ----------------
__global__ __launch_bounds__(256) void attn_kernel(
    const _Float16* __restrict__ qkv,   // [NT, 3D] fp16 (Q at 0, K at D)
    const _Float16* __restrict__ vt,    // [B*NH*64, T] fp16 (V transposed)
    _Float16* __restrict__ o) {         // [NT, D] fp16
  const int qt   = (int)gridDim.x - 1 - (int)blockIdx.x;
  const int h    = blockIdx.y;
  const int b    = blockIdx.z;
  const int tid  = threadIdx.x;
  const int lane = tid & 63, wave = tid >> 6;
  const int lr = lane & 15, g = lane >> 4;
  const int lk = g * 8;   // frag k-offset (halves)
  const int cr = g * 4;   // C-fragment row base

  __shared__ __align__(16) _Float16 Ks[2][2][64][32];   // [buf][dstep][key][d-half]
  __shared__ __align__(16) _Float16 Vs[2][2][64][32];   // [buf][kstep][d][key-half]
  __shared__ __align__(16) _Float16 Pl[4][16][72];      // per-wave P[q][k]

  const int RS = 3 * D;
  const int q0 = qt * 64 + wave * 16;

  const _Float16* qrow = qkv + (size_t)(b * T + q0 + lr) * RS + h * 64;
  half8_t aq0 = *(const half8_t*)(qrow + lk);
  half8_t aq1 = *(const half8_t*)(qrow + 32 + lk);
  #pragma unroll
  for (int j = 0; j < 8; ++j) { aq0[j] *= (_Float16)0.125f; aq1[j] *= (_Float16)0.125f; }

  const int sr = wave * 16 + (lane >> 2);
  const int sc = (lane & 3) * 8;
  const _Float16* ksrc = qkv + (size_t)(b * T + sr) * RS + D + h * 64 + sc;
  const _Float16* vsrc = vt + (size_t)((b * NH + h) * 64 + sr) * T + sc;

#define ASTAGE(bufn, kk) do {                                   \
    const _Float16* kp_ = ksrc + (size_t)((kk) * 64) * RS;      \
    gld16(kp_,      &Ks[bufn][0][wave * 16][0]);                \
    gld16(kp_ + 32, &Ks[bufn][1][wave * 16][0]);                \
    gld16(vsrc + (kk) * 64,      &Vs[bufn][0][wave * 16][0]);   \
    gld16(vsrc + (kk) * 64 + 32, &Vs[bufn][1][wave * 16][0]);   \
  } while (0)

  floatx4 oa[4] = {};
  float m_r[4] = {-1e30f, -1e30f, -1e30f, -1e30f};
  float l_r[4] = {0.f, 0.f, 0.f, 0.f};

  ASTAGE(0, 0);
  __syncthreads();   // compiler drains vmcnt(0) before barrier

  for (int kt = 0; kt <= qt; ++kt) {
    const int cur = kt & 1;
    if (kt < qt) ASTAGE(cur ^ 1, kt + 1);   // prefetch next tile (overlaps compute)

    floatx4 s4[4];
    #pragma unroll
    for (int kc = 0; kc < 4; ++kc) {
      half8_t bk0 = *(const half8_t*)&Ks[cur][0][kc * 16 + lr][lk];
      half8_t bk1 = *(const half8_t*)&Ks[cur][1][kc * 16 + lr][lk];
      floatx4 z = {};
      z = __builtin_amdgcn_mfma_f32_16x16x32_f16(aq0, bk0, z, 0, 0, 0);
      z = __builtin_amdgcn_mfma_f32_16x16x32_f16(aq1, bk1, z, 0, 0, 0);
      s4[kc] = z;
    }
    if (kt == qt) {
      #pragma unroll
      for (int kc = 0; kc < 4; ++kc)
        #pragma unroll
        for (int i = 0; i < 4; ++i)
          if (kc * 16 + lr > wave * 16 + cr + i) s4[kc][i] = -1e30f;
    }

    float alpha[4], psum[4];
    #pragma unroll
    for (int i = 0; i < 4; ++i) {
      float v = fmaxf(fmaxf(s4[0][i], s4[1][i]), fmaxf(s4[2][i], s4[3][i]));
      #pragma unroll
      for (int off = 1; off < 16; off <<= 1) v = fmaxf(v, __shfl_xor(v, off, 64));
      float mn = fmaxf(m_r[i], v);
      alpha[i] = __expf(m_r[i] - mn);
      m_r[i] = mn;
      psum[i] = 0.f;
    }
    #pragma unroll
    for (int kc = 0; kc < 4; ++kc)
      #pragma unroll
      for (int i = 0; i < 4; ++i) {
        float p = __expf(s4[kc][i] - m_r[i]);
        psum[i] += p;
        Pl[wave][cr + i][kc * 16 + lr] = (_Float16)p;
      }
    #pragma unroll
    for (int i = 0; i < 4; ++i) {
      float s = psum[i];
      #pragma unroll
      for (int off = 1; off < 16; off <<= 1) s += __shfl_xor(s, off, 64);
      l_r[i] = l_r[i] * alpha[i] + s;
    }
    #pragma unroll
    for (int dc = 0; dc < 4; ++dc)
      #pragma unroll
      for (int i = 0; i < 4; ++i) oa[dc][i] *= alpha[i];

    half8_t ap0 = *(const half8_t*)&Pl[wave][lr][lk];
    half8_t ap1 = *(const half8_t*)&Pl[wave][lr][32 + lk];
    #pragma unroll
    for (int dc = 0; dc < 4; ++dc) {
      half8_t bv0 = *(const half8_t*)&Vs[cur][0][dc * 16 + lr][lk];
      half8_t bv1 = *(const half8_t*)&Vs[cur][1][dc * 16 + lr][lk];
      oa[dc] = __builtin_amdgcn_mfma_f32_16x16x32_f16(ap0, bv0, oa[dc], 0, 0, 0);
      oa[dc] = __builtin_amdgcn_mfma_f32_16x16x32_f16(ap1, bv1, oa[dc], 0, 0, 0);
    }
    __syncthreads();   // one barrier per tile: drains prefetch + protects buffers
  }
#undef ASTAGE

  _Float16* orow = o + (size_t)(b * T + q0) * D + h * 64;
  #pragma unroll
  for (int i = 0; i < 4; ++i) {
    float inv = 1.f / l_r[i];
    #pragma unroll
    for (int dc = 0; dc < 4; ++dc)
      orow[(size_t)(cr + i) * D + dc * 16 + lr] = (_Float16)(oa[dc][i] * inv);
  }
}

// ---------------- fp16 MFMA GEMM: 3-stage pipeline, counted vmcnt ----------------
// C[M,N] = A[M,K] @ Bt[N,K]^T (+bias,+res,+GELU). A,Bt fp16 K-contiguous.
// Tile BM x 128, 2*BM threads, wave tile 64x64 (4x4 frags).
// Prefetch distance 2: stage i+2 issued at iter i; s_waitcnt vmcnt(2*LPS)
// leaves the two newer stages in flight across the barrier (never drain to 0
// in the main loop). Per-wave wait-own-loads + s_barrier => stage(cur) fully
// visible to all waves. sched_barrier(0) fences both barrier edges (rule #18).
// n-major XCD-chunked tile mapping; split-K via ATOMIC; VT scatters V third
// transposed; NTS: staged LDS epilogue + full-line non-temporal stores.
template <int BM, bool GELU, bool VT, bool ATOMIC, bool NTS, typename OutT>
__global__ __launch_bounds__(2 * BM) void gemm16_kernel(
    const _Float16* __restrict__ A, const _Float16* __restrict__ Bt,
    const float* __restrict__ bias, const float* __restrict__ res,
    OutT* __restrict__ C, _Float16* __restrict__ vt, int M, int N, int K) {
  constexpr int LPS = (BM == 128) ? 4 : 3;     // gld16 per wave per stage
  constexpr int ABYTES = BM * 32 * 2;
  constexpr int BBYTES = 128 * 32 * 2;
  __shared__ __align__(16) char smem_raw[3 * (ABYTES + BBYTES)];
  auto As = (_Float16(*)[BM][32])smem_raw;                    // [3][BM][32]
  auto Bs = (_Float16(*)[128][32])(smem_raw + 3 * ABYTES);    // [3][128][32]

  const int t = threadIdx.x;
  const int lane = t & 63, wave = t >> 6;

  // n-major XCD-chunked tile mapping (nwg % 8 == 0 in all launches)
  const int gx = gridDim.x, gy = gridDim.y;
  const int nwg = gx * gy;
  int f = blockIdx.y * gx + blockIdx.x;         // HW dispatch order (x fastest)
  int id = (f & 7) * (nwg >> 3) + (f >> 3);     // XCD gets contiguous chunk
  const int n0 = (id / gy) * 128;               // n-major within chunk
  const int m0 = (id % gy) * BM;

  // split-K range
  const int ks = K / gridDim.z;
  const int kbeg = blockIdx.z * ks, kend = kbeg + ks;

  const int wm = (wave >> 1) * 64, wn = (wave & 1) * 64;
  const int lr = lane & 15;            // frag row (A) / frag col (B)
  const int lk = (lane >> 4) * 8;      // frag k-offset (halves)

  const int srow = lane >> 2;          // 0..15
  const int scol = (lane & 3) * 8;     // halves
  const _Float16* a_src0 = A + (size_t)(m0 + wave * 32 + srow) * K + scol;
  const _Float16* a_src1 = a_src0 + (size_t)16 * K;
  const int brow = (BM == 128) ? wave * 32 : wave * 16;
  const int bn0 = min(n0 + brow + srow, N - 1);            // clamp (logits tail)
  const int bn1 = min(n0 + brow + 16 + srow, N - 1);       // BM==128 only
  const _Float16* b_src0 = Bt + (size_t)bn0 * K + scol;
  const _Float16* b_src1 = Bt + (size_t)bn1 * K + scol;

  auto GSTAGE = [&](int s, int kk) {
    gld16(a_src0 + kk, &As[s][wave * 32][0]);
    gld16(a_src1 + kk, &As[s][wave * 32 + 16][0]);
    if constexpr (BM == 128) {
      gld16(b_src0 + kk, &Bs[s][wave * 32][0]);
      gld16(b_src1 + kk, &Bs[s][wave * 32 + 16][0]);
    } else {
      gld16(b_src0 + kk, &Bs[s][wave * 16][0]);
    }
  };

  floatx4 acc[4][4] = {};
  const int nIter = (kend - kbeg) >> 5;

  GSTAGE(0, kbeg);
  if (nIter > 1) GSTAGE(1, kbeg + 32);

  int cur = 0, nxt = 2;
  for (int i = 0; i < nIter; ++i) {
    const int rem = nIter - 1 - i;                 // stages beyond current
    if (rem >= 2) { GSTAGE(nxt, kbeg + ((i + 2) << 5)); waitvm<2 * LPS>(); }
    else if (rem == 1) waitvm<LPS>();
    else waitvm<0>();
    __builtin_amdgcn_s_barrier();                  // all waves' stage(cur) visible
    __builtin_amdgcn_sched_barrier(0);

    half8_t af[4], bb[4];
    #pragma unroll
    for (int mi = 0; mi < 4; ++mi)
      af[mi] = *(const half8_t*)&As[cur][wm + mi * 16 + lr][lk];
    #pragma unroll
    for (int ni = 0; ni < 4; ++ni)
      bb[ni] = *(const half8_t*)&Bs[cur][wn + ni * 16 + lr][lk];
    #pragma unroll
    for (int mi = 0; mi < 4; ++mi)
      #pragma unroll
      for (int ni = 0; ni < 4; ++ni)
        acc[mi][ni] = __builtin_amdgcn_mfma_f32_16x16x32_f16(
            af[mi], bb[ni], acc[mi][ni], 0, 0, 0);

    __builtin_amdgcn_sched_barrier(0);
    __builtin_amdgcn_s_barrier();                  // reads retired; rotation safe
    __builtin_amdgcn_sched_barrier(0);             // next-iter loads stay below
    cur = (cur == 2) ? 0 : cur + 1;
    nxt = (nxt == 2) ? 0 : nxt + 1;
  }

  const int cr = (lane >> 4) * 4;

  if constexpr (NTS) {
    // staged epilogue: per 64-row band, dump acc to LDS fp32 [64][132],
    // then stream out contiguous full-line non-temporal stores.
    constexpr int THREADS = 2 * BM;
    constexpr int RPP = THREADS / 128;     // rows per pass
    float (*ob)[132] = (float(*)[132])smem_raw;
    #pragma unroll
    for (int h2 = 0; h2 < BM / 64; ++h2) {
      __syncthreads();
      if ((wave >> 1) == h2) {
        #pragma unroll
        for (int mi = 0; mi < 4; ++mi)
          #pragma unroll
          for (int ni = 0; ni < 4; ++ni) {
            floatx4 v = acc[mi][ni];
            #pragma unroll
            for (int i = 0; i < 4; ++i)
              ob[mi * 16 + cr + i][wn + ni * 16 + lr] = v[i];
          }
      }
      __syncthreads();
      const int col = t & 127;
      const int rbase = t >> 7;
      const int n = n0 + col;
      if (n < N) {
        #pragma unroll
        for (int r2 = 0; r2 < 64 / RPP; ++r2) {
          int rloc = r2 * RPP + rbase;
          int m = m0 + h2 * 64 + rloc;
          __builtin_nontemporal_store((OutT)ob[rloc][col], &C[(size_t)m * N + n]);
        }
      }
    }
    return;
  }

  // epilogue: C/D layout col=lane&15, row=(lane>>4)*4+reg
  #pragma unroll
  for (int mi = 0; mi < 4; ++mi) {
    #pragma unroll
    for (int ni = 0; ni < 4; ++ni) {
      int n = n0 + wn + ni * 16 + lr;
      if (n >= N) continue;
      floatx4 v = acc[mi][ni];
      float bs = (bias && (!ATOMIC || blockIdx.z == 0)) ? bias[n] : 0.f;
      if (VT && n >= 2 * D) {
        int d  = n - 2 * D;
        int mb = m0 + wm + mi * 16 + cr;
        half4_t h4;
        #pragma unroll
        for (int i = 0; i < 4; ++i) h4[i] = (_Float16)(v[i] + bs);
        *(half4_t*)(vt + ((size_t)((mb >> 10) * NH + (d >> 6)) * 64 + (d & 63)) * T
                       + (mb & 1023)) = h4;
      } else if (ATOMIC) {
        #pragma unroll
        for (int i = 0; i < 4; ++i) {
          int m = m0 + wm + mi * 16 + cr + i;
          atomicAdd((float*)&C[(size_t)m * N + n], v[i] + bs);
        }
      } else {
        #pragma unroll
        for (int i = 0; i < 4; ++i) {
          int m = m0 + wm + mi * 16 + cr + i;
          float vv = v[i] + bs;
          if (res)  vv += res[(size_t)m * N + n];
          if (GELU) vv = 0.5f * vv * (1.f + erff(vv * 0.70710678118f));
          C[(size_t)m * N + n] = (OutT)vv;
        }
      }
    }
  }
}

// ---------------- launcher ----------------
extern "C" void kernel_launch(void* const* d_in, const int* in_sizes, int n_in,
                              void* d_out, int out_size, void* d_ws, size_t ws_size,
                              hipStream_t stream) {
  const int*   idx   = (const int*)d_in[0];
  const float* wte   = (const float*)d_in[1];
  const float* pos   = (const float*)d_in[2];
  const float* ln1g  = (const float*)d_in[3];
  const float* ln1b  = (const float*)d_in[4];
  const float* qkvw  = (const float*)d_in[5];
  const float* qkvb  = (const float*)d_in[6];
  const float* projw = (const float*)d_in[7];
  const float* projb = (const float*)d_in[8];
  const float* ln2g  = (const float*)d_in[9];
  const float* ln2b  = (const float*)d_in[10];
  const float* fc1w  = (const float*)d_in[11];
  const float* fc1b  = (const float*)d_in[12];
  const float* fc2w  = (const float*)d_in[13];
  const float* fc2b  = (const float*)d_in[14];
  const float* lnfg  = (const float*)d_in[15];
  const float* lnfb  = (const float*)d_in[16];
  float* out = (float*)d_out;

  // ---- workspace layout ----
  float* ws = (float*)d_ws;
  float* x = ws;                                        // [NT, D] f32 residual
  _Float16* big16  = (_Float16*)(x + (size_t)NT * D);   // [NT,4D]
  _Float16* vt16   = big16 + (size_t)NT * 4 * D;        // [B*NH*64, T]
  _Float16* hbuf16 = vt16 + (size_t)BATCH * NH * 64 * T;// [NT, D]
  _Float16* obuf16 = hbuf16 + (size_t)NT * D;           // [NT, D]
  _Float16* wte16  = obuf16 + (size_t)NT * D;           // [V, D]
  _Float16* wbase  = wte16 + (size_t)V * D;             // weights (1 or 12 layers)

  const size_t QSZ = (size_t)2304 * 768, PSZ = (size_t)768 * 768;
  const size_t F1SZ = (size_t)3072 * 768, F2SZ = (size_t)3072 * 768;
  const size_t PERL = QSZ + PSZ + F1SZ + F2SZ;          // 7,077,888 halves
  const size_t fixed_bytes = (char*)wbase - (char*)d_ws;
  const bool all12 = ws_size >= fixed_bytes + 12 * PERL * sizeof(_Float16);
  const int nlw = all12 ? 12 : 1;

  _Float16* q16  = wbase;
  _Float16* p16  = q16  + QSZ * nlw;
  _Float16* f116 = p16  + PSZ * nlw;
  _Float16* f216 = f116 + F1SZ * nlw;

  cvt16_kernel<<<2048, 256, 0, stream>>>(wte, wte16, (V * D) / 4);
  embed_kernel<<<NT, 256, 0, stream>>>(idx, wte, pos, x);
  if (all12)
    wconv_kernel<<<dim3(6912, 12), 256, 0, stream>>>(
        qkvw, projw, fc1w, fc2w, q16, p16, f116, f216);

  for (int l = 0; l < NL; ++l) {
    size_t lw = all12 ? (size_t)l : 0;
    if (!all12)
      wconv_kernel<<<dim3(6912, 1), 256, 0, stream>>>(
          qkvw + (size_t)l * D * 3 * D, projw + (size_t)l * D * D,
          fc1w + (size_t)l * D * 4 * D, fc2w + (size_t)l * 4 * D * D,
          q16, p16, f116, f216);
    // ln1 -> fp16
    ln_kernel<<<NT / 4, 256, 0, stream>>>(x, ln1g + (size_t)l * D, ln1b + (size_t)l * D, hbuf16);
    // qkv: Q,K -> big16 [NT,3D]; V -> vt16 transposed
    gemm16_kernel<128, false, true, false, false, _Float16><<<dim3(18, 16), 256, 0, stream>>>(
        hbuf16, q16 + lw * QSZ, qkvb + (size_t)l * 3 * D, nullptr, big16, vt16, NT, 3 * D, D);
    // flash attention -> obuf16
    attn_kernel<<<dim3(T / 64, NH, BATCH), 256, 0, stream>>>(big16, vt16, obuf16);
    // x += o @ proj_w + proj_b  (split-K=2, atomic into residual)
    gemm16_kernel<128, false, false, true, false, float><<<dim3(6, 16, 2), 256, 0, stream>>>(
        obuf16, p16 + lw * PSZ, projb + (size_t)l * D, nullptr, x, nullptr, NT, D, D);
    // ln2 -> fp16
    ln_kernel<<<NT / 4, 256, 0, stream>>>(x, ln2g + (size_t)l * D, ln2b + (size_t)l * D, hbuf16);
    // fc1 + GELU -> big16 (fp16 [NT,4D])
    gemm16_kernel<128, true, false, false, false, _Float16><<<dim3(24, 16), 256, 0, stream>>>(
        hbuf16, f116 + lw * F1SZ, fc1b + (size_t)l * 4 * D, nullptr, big16, nullptr, NT, 4 * D, D);
    // x += gelu @ fc2_w + fc2_b  (split-K=4, atomic into residual)
    gemm16_kernel<128, false, false, true, false, float><<<dim3(6, 16, 4), 256, 0, stream>>>(
        big16, f216 + lw * F2SZ, fc2b + (size_t)l * D, nullptr, x, nullptr, NT, D, 4 * D);
  }

  // final LN -> fp16
  ln_kernel<<<NT / 4, 256, 0, stream>>>(x, lnfg, lnfb, hbuf16);
  // logits = h @ wte^T  [NT, V]: 256x128 tile + staged full-line NT stores
  gemm16_kernel<256, false, false, false, true, float><<<dim3((V + 127) / 128, 8), 512, 0, stream>>>(
      hbuf16, wte16, nullptr, nullptr, out, nullptr, NT, V, D);
}